// Round 2
// baseline (165.241 us; speedup 1.0000x reference)
//
#include <hip/hip_runtime.h>
#include <hip/hip_bf16.h>
#include <stdint.h>

#define LN_EPS 1e-5f

typedef __attribute__((ext_vector_type(4))) float f32x4;
typedef __attribute__((ext_vector_type(8))) short bf16x8;

#define B_ 8
#define S_ 4096
#define D_ 1024
#define P_ 512
#define N_ (B_*S_)   // 32768 rows

// async global->LDS, 16B per lane
__device__ __forceinline__ void gload_lds16(const void* gsrc, void* ldst) {
  __builtin_amdgcn_global_load_lds(
      (const __attribute__((address_space(1))) void*)gsrc,
      (__attribute__((address_space(3))) void*)ldst,
      16, 0, 0);
}

// ---------------- kernel: scatter W rows into W2f ----------------
// W2f[c,p] = sum_{d: s5[d]==c} W[d,p];  b2[c] = sum_{d: s5[d]==c} b[d]
__global__ void k_scatter(const float* __restrict__ W, const float* __restrict__ bias,
                          const int* __restrict__ s5,
                          float* __restrict__ w2f, float* __restrict__ b2) {
  int d = blockIdx.x;                  // 0..1023
  int c = s5[d];
  const float* wrow = W + (size_t)d * P_;
  float* dst = w2f + (size_t)c * P_;
  for (int p = threadIdx.x; p < P_; p += 256)
    atomicAdd(&dst[p], wrow[p]);
  if (threadIdx.x == 0) atomicAdd(&b2[c], bias[d]);
}

// ---------------- kernel: W2f -> bf16 ----------------
__global__ void k_conv(const float* __restrict__ w2f, __hip_bfloat16* __restrict__ w2b) {
  int i = blockIdx.x * 256 + threadIdx.x;
  if (i < D_ * P_) w2b[i] = __float2bfloat16(w2f[i]);
}

// ---------------- kernel: LayerNorm + gather -> g (bf16 [N_,P_]) ----------------
__global__ __launch_bounds__(256) void k_ln_gather(
    const float* __restrict__ x, const float* __restrict__ lnw,
    const float* __restrict__ lnb, const int* __restrict__ s3,
    __hip_bfloat16* __restrict__ g) {
  __shared__ float row[D_];
  __shared__ float psum[4], psum2[4];
  const int n = blockIdx.x;
  const int t = threadIdx.x;
  const float* xr = x + (size_t)n * D_;
  float4 v = ((const float4*)xr)[t];       // 256 threads * 4 floats = 1024
  ((float4*)row)[t] = v;
  float s  = v.x + v.y + v.z + v.w;
  float s2 = v.x*v.x + v.y*v.y + v.z*v.z + v.w*v.w;
  #pragma unroll
  for (int off = 32; off > 0; off >>= 1) {
    s  += __shfl_down(s, off);
    s2 += __shfl_down(s2, off);
  }
  const int lane = t & 63, wid = t >> 6;
  if (lane == 0) { psum[wid] = s; psum2[wid] = s2; }
  __syncthreads();
  const float tot  = psum[0] + psum[1] + psum[2] + psum[3];
  const float tot2 = psum2[0] + psum2[1] + psum2[2] + psum2[3];
  const float mu  = tot * (1.f / D_);
  const float var = tot2 * (1.f / D_) - mu * mu;
  const float inv = rsqrtf(var + LN_EPS);
  __hip_bfloat16* gr = g + (size_t)n * P_;
  // two gathered outputs per thread, one 4B store
  const int i0 = s3[2*t], i1 = s3[2*t+1];
  const float v0 = (row[i0] - mu) * inv * lnw[i0] + lnb[i0];
  const float v1 = (row[i1] - mu) * inv * lnw[i1] + lnb[i1];
  union { __hip_bfloat16 h; unsigned short u; } c0, c1;
  c0.h = __float2bfloat16(v0);
  c1.h = __float2bfloat16(v1);
  unsigned int packed = (unsigned int)c0.u | ((unsigned int)c1.u << 16);
  ((unsigned int*)gr)[t] = packed;
}

// ---------------- kernel: bf16 MFMA GEMM + residual + bias ----------------
// out[n,c] = hid[n,c] + sum_p g[n,p]*W2[c,p] + b2[c]
// 128x128 tile, BK=32, DOUBLE-buffered (LDS 32KB total -> 4 blocks/CU via VGPR),
// 4 waves (2x2), 16x16x32 bf16 MFMA, acc 4x4 frags/wave.
// LDS tiles row-major [128][32] bf16 (64B rows), XOR swizzle byte^=((row&3)<<4);
// swizzle applied on the *global source* 16B-chunk index (global_load_lds writes
// linearly) and on the ds_read address (both-sides rule).
#define BM 128
#define BN 128
#define BK 32

__global__ __launch_bounds__(256, 4) void k_gemm(
    const __hip_bfloat16* __restrict__ g,    // [N_,P_]
    const __hip_bfloat16* __restrict__ w2b,  // [D_,P_]
    const float* __restrict__ b2,            // [D_]
    const float* __restrict__ hid,           // [N_,D_]
    float* __restrict__ out) {               // [N_,D_]
  __shared__ char At[2][BM * BK * 2];        // 2 x 8KB
  __shared__ char Bt[2][BN * BK * 2];        // 2 x 8KB

  // XCD-aware swizzle: dispatch round-robins bid%8 across XCDs. Give XCD x a
  // contiguous range of 32 bm-strips, with the 8 bn-siblings of each strip all
  // on the same XCD (they share the A strip -> XCD-local L2 reuse).
  const int bid = blockIdx.x;                // 0..2047
  const int x = bid & 7;                     // this block's XCD
  const int kq = bid >> 3;                   // 0..255
  const int bm = (x * 32 + (kq >> 3)) * BM;  // row tile
  const int bn = (kq & 7) * BN;              // col tile

  const int t = threadIdx.x;
  const int lane = t & 63;
  const int wid = t >> 6;
  const int wr = wid >> 1, wc = wid & 1;     // 2x2 waves, 64x64 subtile each

  f32x4 acc[4][4] = {};

  // stage tile ks into buf: 512 chunks of 16B per operand, 2 per thread
  #define STAGE(ks, buf)                                                      \
    {                                                                         \
      const int k0 = (ks) * BK;                                               \
      _Pragma("unroll")                                                       \
      for (int i = 0; i < 2; ++i) {                                           \
        int ch = t + i * 256;                 /* 0..511 */                     \
        int r  = ch >> 2;                     /* tile row, 4 x 16B per 64B row */ \
        int cc = ch & 3;                                                      \
        int col = ((cc ^ (r & 3)) << 3);      /* pre-swizzled src col (bf16) */ \
        gload_lds16(g   + (size_t)(bm + r) * P_ + k0 + col, At[buf] + ch * 16); \
        gload_lds16(w2b + (size_t)(bn + r) * P_ + k0 + col, Bt[buf] + ch * 16); \
      }                                                                       \
    }

  STAGE(0, 0);
  for (int ks = 0; ks < 16; ++ks) {
    const int buf = ks & 1;
    __syncthreads();                  // compiler drains vmcnt+lgkmcnt here:
                                      // tile ks staged, prev reads complete
    if (ks < 15) STAGE(ks + 1, buf ^ 1);   // flies under this step's compute

    const int colb = (lane >> 4) << 4;     // byte offset of 8-elem k-group
    bf16x8 af[4], bfr[4];
    #pragma unroll
    for (int mi = 0; mi < 4; ++mi) {
      int r = wr * 64 + mi * 16 + (lane & 15);
      af[mi] = *(const bf16x8*)(At[buf] + ((r * 64 + colb) ^ ((r & 3) << 4)));
    }
    #pragma unroll
    for (int ni = 0; ni < 4; ++ni) {
      int r = wc * 64 + ni * 16 + (lane & 15);
      bfr[ni] = *(const bf16x8*)(Bt[buf] + ((r * 64 + colb) ^ ((r & 3) << 4)));
    }
    #pragma unroll
    for (int mi = 0; mi < 4; ++mi)
      #pragma unroll
      for (int ni = 0; ni < 4; ++ni)
        acc[mi][ni] = __builtin_amdgcn_mfma_f32_16x16x32_bf16(af[mi], bfr[ni], acc[mi][ni], 0, 0, 0);
  }

  // epilogue: C/D layout col=lane&15 (N), row=(lane>>4)*4+reg (M)
  const int row0 = bm + wr * 64 + ((lane >> 4) << 2);
  const int col0 = bn + wc * 64 + (lane & 15);
  #pragma unroll
  for (int ni = 0; ni < 4; ++ni) {
    const int col = col0 + ni * 16;
    const float bias = b2[col];
    #pragma unroll
    for (int mi = 0; mi < 4; ++mi) {
      const int rw = row0 + mi * 16;
      #pragma unroll
      for (int r = 0; r < 4; ++r) {
        size_t idx = (size_t)(rw + r) * D_ + col;
        out[idx] = hid[idx] + acc[mi][ni][r] + bias;
      }
    }
  }
}

extern "C" void kernel_launch(void* const* d_in, const int* in_sizes, int n_in,
                              void* d_out, int out_size, void* d_ws, size_t ws_size,
                              hipStream_t stream) {
  const float* hid  = (const float*)d_in[0];
  const float* lnw  = (const float*)d_in[1];
  const float* lnb  = (const float*)d_in[2];
  const float* W    = (const float*)d_in[3];
  const float* bias = (const float*)d_in[4];
  const int*   s3   = (const int*)d_in[5];
  const int*   s5   = (const int*)d_in[6];
  float* out = (float*)d_out;

  // workspace layout (all 256B-aligned):
  //   [0, 2MB)        W2f  fp32 [1024][512]
  //   [2MB, +4KB)     b2   fp32 [1024]
  //   [2MB+4KB, +1MB) W2b  bf16 [1024][512]
  //   [3MB+4KB, +32MB) g   bf16 [32768][512]
  char* ws = (char*)d_ws;
  float*          w2f = (float*)ws;
  float*          b2  = (float*)(ws + 2097152);
  __hip_bfloat16* w2b = (__hip_bfloat16*)(ws + 2101248);
  __hip_bfloat16* g   = (__hip_bfloat16*)(ws + 3149824);

  hipMemsetAsync(ws, 0, 2101248, stream);   // zero W2f + b2
  k_scatter<<<dim3(1024), dim3(256), 0, stream>>>(W, bias, s5, w2f, b2);
  k_conv   <<<dim3(2048), dim3(256), 0, stream>>>(w2f, w2b);
  k_ln_gather<<<dim3(N_), dim3(256), 0, stream>>>(hid, lnw, lnb, s3, g);
  k_gemm   <<<dim3(2048), dim3(256), 0, stream>>>(g, w2b, b2, hid, out);
}